// Round 2
// 713.842 us; speedup vs baseline: 1.0980x; 1.0980x over previous
//
#include <hip/hip_runtime.h>
#include <math.h>

// VQ-VAE forward. R14: verified R12 two-stage encoder (conv1n + MODE2 mconv)
// restored; composed decoder (deconv1∘deconv2 = single k10s4 transposed conv,
// validated in R13) kept. R13's composed ENCODER is reverted: it broke the
// loss output (z-sensitive) while recon (z-insensitive) passed — bug isolated
// to the encoder composition trio, to be re-attacked against this baseline.

typedef unsigned short ushort;
typedef short bf16x8 __attribute__((ext_vector_type(8)));
typedef float f32x4 __attribute__((ext_vector_type(4)));

__device__ __forceinline__ ushort f2bf(float f) {
    unsigned u = __builtin_bit_cast(unsigned, f);
    unsigned r = (u + 0x7fffu + ((u >> 16) & 1u)) >> 16;
    return (ushort)r;
}
__device__ __forceinline__ float bfl(unsigned u) { return __builtin_bit_cast(float, u << 16); }
__device__ __forceinline__ float bfh(unsigned u) { return __builtin_bit_cast(float, u & 0xffff0000u); }

__device__ __forceinline__ unsigned relu_u(unsigned u) {
    unsigned m = (u >> 15) & 0x00010001u;
    return u & ~((m << 16) - m);
}
__device__ __forceinline__ uint4 relu4(uint4 v) {
    v.x = relu_u(v.x); v.y = relu_u(v.y); v.z = relu_u(v.z); v.w = relu_u(v.w);
    return v;
}

// ======================= weight packing =======================
// MFMA layout (per layer): [cls][tap][cb(8)][co(256)][k(32)] bf16.

__global__ void k_pack_c3x4(const float* __restrict__ w0, const float* __restrict__ w1,
                            const float* __restrict__ w2, const float* __restrict__ w3,
                            ushort* __restrict__ o0, ushort* __restrict__ o1,
                            ushort* __restrict__ o2, ushort* __restrict__ o3) {
    int layer = blockIdx.x / 2304;
    int i = (blockIdx.x - layer * 2304) * 256 + threadIdx.x;     // 589824
    const float* w = layer == 0 ? w0 : layer == 1 ? w1 : layer == 2 ? w2 : w3;
    ushort* o = layer == 0 ? o0 : layer == 1 ? o1 : layer == 2 ? o2 : o3;
    int kk = i & 31, co = (i >> 5) & 255, cb = (i >> 13) & 7, t = i >> 16;
    int ci = cb * 32 + kk, kh = t / 3, kw = t % 3;
    o[i] = f2bf(w[((co * 256 + ci) * 3 + kh) * 3 + kw]);
}

__global__ void k_pack_c1x1x4(const float* __restrict__ w0, const float* __restrict__ w1,
                              const float* __restrict__ w2, const float* __restrict__ w3,
                              ushort* __restrict__ o0, ushort* __restrict__ o1,
                              ushort* __restrict__ o2, ushort* __restrict__ o3) {
    int layer = blockIdx.x >> 8;
    int i = (blockIdx.x & 255) * 256 + threadIdx.x;              // 65536
    const float* w = layer == 0 ? w0 : layer == 1 ? w1 : layer == 2 ? w2 : w3;
    ushort* o = layer == 0 ? o0 : layer == 1 ? o1 : layer == 2 ? o2 : o3;
    int kk = i & 31, co = (i >> 5) & 255, cb = (i >> 13) & 7;
    o[i] = f2bf(w[co * 256 + cb * 32 + kk]);
}

// conv2 4x4s2 pack: [cls(4 phase)][tap(4)][cb(8)][co(256)][k(32)]
__global__ void k_pack_c2(const float* __restrict__ wc2, ushort* __restrict__ oc2) {
    int i = blockIdx.x * 256 + threadIdx.x;                      // 1048576
    int kk = i & 31, co = (i >> 5) & 255, cb = (i >> 13) & 7;
    int t = (i >> 16) & 3, cls = i >> 18;
    int a = t >> 1, b = t & 1, ci = cb * 32 + kk;
    int ph = cls >> 1, pw = cls & 1;
    int kh = ph ? 2 * a : 2 * a + 1;
    int kw = pw ? 2 * b : 2 * b + 1;
    oc2[i] = f2bf(wc2[((co * 256 + ci) * 4 + kh) * 4 + kw]);
}

__global__ void k_pack_c1f(const float* __restrict__ w, float* __restrict__ o) {
    int i = blockIdx.x * 256 + threadIdx.x;           // 12288
    int co = i & 255, k = i >> 8;
    int ci = k >> 4, kh = (k >> 2) & 3, kw = k & 3;
    o[k * 256 + co] = w[((co * 3 + ci) * 4 + kh) * 4 + kw];
}

__global__ void k_pack_vq(const float* __restrict__ cb, ushort* __restrict__ apk,
                          float* __restrict__ en) {
    if (blockIdx.x < 64) {
        int i = blockIdx.x * 256 + threadIdx.x;
        int j = i & 7, lane = (i >> 3) & 63, s = (i >> 9) & 1, t = i >> 10;
        int code = t * 16 + (lane & 15);
        int dim = s * 32 + (lane >> 4) * 8 + j;
        apk[i] = f2bf(cb[code * 64 + dim]);
    } else {
        int code = threadIdx.x;
        float s = 0.f;
        for (int d = 0; d < 64; ++d) { float v = cb[code * 64 + d]; s += v * v; }
        en[code] = s;
    }
}

// ======================= decoder weight composition =======================
// out[o,Y,X] = sum_{ci,du,dv} in[ci,U+du,V+dv] * W_eff[o,ci, py+3-4du, px+3-4dv]
// W_eff[o,ci,y,x] = sum_{(a,c):2a+c=y} sum_{(b,d):2b+d=x} sum_m dt1[ci,m,a,b]*dt2[m,o,c,d]
// packed wdec[t=(du+1)*3+(dv+1)][o(3)][cb(8)][p=py*4+px(16)][kk(32)] (pre-zeroed).
__global__ __launch_bounds__(256) void k_wcomp_dec(const float* __restrict__ dt1,
                                                   const float* __restrict__ dt1b,
                                                   const float* __restrict__ dt2,
                                                   const float* __restrict__ dt2b,
                                                   ushort* __restrict__ wdec,
                                                   float* __restrict__ bdec) {
    __shared__ float s1[4096];     // dt1[ci][m][a][b] slice (16KB)
    __shared__ float s2[12288];    // dt2[m][o][c][d]        (49KB)
    __shared__ float part[2400];
    int ci = blockIdx.x, tid = threadIdx.x;
    for (int i = tid; i < 4096; i += 256) s1[i] = dt1[ci * 4096 + i];
    for (int i = tid; i < 12288; i += 256) s2[i] = dt2[i];
    __syncthreads();

    if (ci == 0 && tid < 48) {     // composed bias per (o, phase)
        int o = tid >> 4, p = tid & 15, py = p >> 2, px = p & 3;
        int c0 = (py + 1) & 1, d0 = (px + 1) & 1;
        float s = dt2b[o];
        for (int m = 0; m < 256; ++m) {
            float t2 = s2[m * 48 + o * 16 + c0 * 4 + d0] + s2[m * 48 + o * 16 + c0 * 4 + d0 + 2]
                     + s2[m * 48 + o * 16 + (c0 + 2) * 4 + d0] + s2[m * 48 + o * 16 + (c0 + 2) * 4 + d0 + 2];
            s += dt1b[m] * t2;
        }
        bdec[tid] = s;
    }

    if (tid < 240) {               // t = y*24 + o*8 + ms
        int y = tid / 24, rem = tid % 24, o = rem / 8, ms = rem % 8;
        int na = 0, aa[2], cc[2];
#pragma unroll
        for (int a = 0; a < 4; ++a) {
            int c = y - 2 * a;
            if ((unsigned)c < 4u) { aa[na] = a; cc[na] = c; ++na; }
        }
        float acc10[10];
#pragma unroll
        for (int xx = 0; xx < 10; ++xx) acc10[xx] = 0.f;
        for (int m = ms * 32; m < ms * 32 + 32; ++m) {
            for (int pa = 0; pa < na; ++pa) {
                float4 d1 = *(const float4*)&s1[m * 16 + aa[pa] * 4];
                float4 d2 = *(const float4*)&s2[m * 48 + o * 16 + cc[pa] * 4];
                // acc10[2*b + d] += d1[b] * d2[d]
                acc10[0] += d1.x * d2.x; acc10[1] += d1.x * d2.y; acc10[2] += d1.x * d2.z; acc10[3] += d1.x * d2.w;
                acc10[2] += d1.y * d2.x; acc10[3] += d1.y * d2.y; acc10[4] += d1.y * d2.z; acc10[5] += d1.y * d2.w;
                acc10[4] += d1.z * d2.x; acc10[5] += d1.z * d2.y; acc10[6] += d1.z * d2.z; acc10[7] += d1.z * d2.w;
                acc10[6] += d1.w * d2.x; acc10[7] += d1.w * d2.y; acc10[8] += d1.w * d2.z; acc10[9] += d1.w * d2.w;
            }
        }
#pragma unroll
        for (int xx = 0; xx < 10; ++xx) part[tid * 10 + xx] = acc10[xx];
    }
    __syncthreads();
    if (tid < 300) {
        int y = tid / 30, r = tid % 30, o = r / 10, xx = r % 10;
        float s = 0.f;
#pragma unroll
        for (int ms = 0; ms < 8; ++ms) s += part[((y * 24 + o * 8) + ms) * 10 + xx];
        int du = (y < 3) ? 1 : (y < 7) ? 0 : -1;
        int py = y - 3 + 4 * du;
        int dv = (xx < 3) ? 1 : (xx < 7) ? 0 : -1;
        int px = xx - 3 + 4 * dv;
        int t = (du + 1) * 3 + (dv + 1);
        int cb2 = ci >> 5, kk = ci & 31;
        wdec[((((t * 3 + o) * 8 + cb2) * 16 + py * 4 + px) * 32) + kk] = f2bf(s);
    }
}

// ======================= conv1: 3->256 k4 s2, 128->64, LDS-staged ==============
__global__ __launch_bounds__(256) void k_conv1n(const float* __restrict__ x,
                                                const float* __restrict__ wt,
                                                const float* __restrict__ bias,
                                                ushort* __restrict__ o) {       // NHWC64 bf16
    __shared__ float sx[12][132];
    int b = blockIdx.x;                  // 32n * 64h
    int h = b & 63, n = b >> 6;
    int tid = threadIdx.x;
    for (int c = tid; c < 12 * 128; c += 256) {
        int t = c >> 7, wi = c & 127;
        int ci = t >> 2, kh = t & 3;
        int hi = 2 * h - 1 + kh;
        float v = ((unsigned)hi < 128u) ? x[((long)n * 3 + ci) * 16384 + hi * 128 + wi] : 0.f;
        sx[t][wi + 1] = v;
    }
    if (tid < 24) { int t = tid >> 1; sx[t][(tid & 1) ? 129 : 0] = 0.f; }
    int co = tid;
    float wr[48];
#pragma unroll
    for (int k = 0; k < 48; ++k) wr[k] = wt[k * 256 + co];
    float bco = bias[co];
    __syncthreads();
    ushort* op = o + (((long)n * 64 + h) * 64) * 256 + co;
    for (int w = 0; w < 64; ++w) {
        float acc = bco;
#pragma unroll
        for (int t = 0; t < 12; ++t) {
            const float* xr = &sx[t][2 * w];
            acc += xr[0] * wr[t * 4] + xr[1] * wr[t * 4 + 1]
                 + xr[2] * wr[t * 4 + 2] + xr[3] * wr[t * 4 + 3];
        }
        op[w * 256] = f2bf(acc);
    }
}

// ======================= wave-private barrier-free MFMA conv ====================
// MODE 0: 3x3 (9 taps)  MODE 1: 1x1  MODE 2: conv2 4x4s2 (4ph x 4 taps)
template <int MODE, bool HAS_BIAS, bool ADD_RES, bool RELU_STAGE, bool RELU_OUT>
__global__ __launch_bounds__(128, 2) void k_mconv(const ushort* __restrict__ xin,
                                                  const ushort* __restrict__ wpk,
                                                  const float* __restrict__ bias,
                                                  const ushort* __restrict__ res,
                                                  ushort* __restrict__ obf) {
    constexpr int NT = (MODE == 0) ? 9 : ((MODE == 1) ? 1 : 4);
    constexpr int NITER = (MODE == 2) ? 32 : 8;
    constexpr int NR = (MODE == 0) ? 4 : ((MODE == 1) ? 2 : 3);
    constexpr int BUFU = NR * 4 * 34 * 8;            // ushorts per buffer
    constexpr int WLDS = 2 * BUFU;                   // per-wave ushorts

    __shared__ __align__(16) ushort sX[2 * WLDS];

    int tid = threadIdx.x, lane = tid & 63, wv = tid >> 6;
    int q = lane >> 4, l15 = lane & 15;
    int b = blockIdx.x;
    int mblk = b & 7, coslab = (b >> 3) & 3;
    int n = b >> 5;
    int R0 = mblk * 4 + wv * 2;                      // wave's first output row

    ushort* sW = sX + wv * WLDS;

    if (lane < 2 * NR * 4 * 2) {
        int cc = (lane & 1) ? 33 : 0;
        int sq = lane >> 1;
        uint4 z; z.x = z.y = z.z = z.w = 0;
        *(uint4*)&sW[(sq * 34 + cc) * 8] = z;
    }

    int brr[4], bcol[4];
#pragma unroll
    for (int bt = 0; bt < 4; ++bt) {
        int p = bt * 16 + l15;
        brr[bt] = p >> 5; bcol[bt] = (p & 31) + 1;
    }

    int scol = lane >> 1, j0 = (lane & 1) * 2;

    int aoff = (coslab * 64 + l15) * 32 + q * 8;

    f32x4 acc[4][4];
#pragma unroll
    for (int at = 0; at < 4; ++at)
#pragma unroll
        for (int bt = 0; bt < 4; ++bt) acc[at][bt] = 0.f;

    uint4 sreg[NR][2];
    auto stage_load = [&](int it2) {
        int cb2 = (MODE == 2) ? (it2 >> 2) : it2;
        int ph2 = (MODE == 2) ? (it2 & 3) : 0;
        int ph_h2 = ph2 >> 1, ph_w2 = ph2 & 1;
        int hh0 = (MODE == 0) ? R0 - 1 : (MODE == 1) ? R0 : R0 - ph_h2;
#pragma unroll
        for (int r = 0; r < NR; ++r) {
            int hh = hh0 + r;
            bool valid = (unsigned)hh < 32u;
            long off;
            if (MODE == 2)
                off = (((long)n * 64 + 2 * hh + ph_h2) * 64 + (2 * scol + ph_w2)) * 256 + cb2 * 32 + j0 * 8;
            else
                off = (((long)n * 32 + hh) * 32 + scol) * 256 + cb2 * 32 + j0 * 8;
#pragma unroll
            for (int k = 0; k < 2; ++k) {
                uint4 v;
                if (valid) {
                    v = *(const uint4*)(xin + off + k * 8);
                    if (RELU_STAGE) v = relu4(v);
                } else { v.x = 0; v.y = 0; v.z = 0; v.w = 0; }
                sreg[r][k] = v;
            }
        }
    };
    auto write_stage = [&](int pbuf) {
        ushort* bufp = sW + pbuf * BUFU;
#pragma unroll
        for (int r = 0; r < NR; ++r)
#pragma unroll
            for (int k = 0; k < 2; ++k)
                *(uint4*)&bufp[((r * 4 + j0 + k) * 34 + scol + 1) * 8] = sreg[r][k];
    };

    stage_load(0);
    write_stage(0);

    for (int it = 0; it < NITER; ++it) {
        int cb = (MODE == 2) ? (it >> 2) : it;
        int ph = (MODE == 2) ? (it & 3) : 0;
        int ph_w = ph & 1;
        int clsi = (MODE == 2) ? ph : 0;
        const ushort* wb = wpk + ((long)(clsi * NT) * 8 + cb) * 8192 + aoff;
        ushort* bufp = sW + (it & 1) * BUFU;

        if (it + 1 < NITER) stage_load(it + 1);   // loads in flight during MFMA

        if (MODE == 0) {
            bf16x8 afc[4];
#pragma unroll
            for (int at = 0; at < 4; ++at) afc[at] = *(const bf16x8*)(wb + at * 512);
#pragma unroll
            for (int t = 0; t < 9; ++t) {
                bf16x8 afn[4];
                if (t < 8) {
#pragma unroll
                    for (int at = 0; at < 4; ++at)
                        afn[at] = *(const bf16x8*)(wb + (long)(t + 1) * 65536 + at * 512);
                }
                int taprow = t / 3, dx = t % 3 - 1;
                bf16x8 bfr[4];
#pragma unroll
                for (int bt = 0; bt < 4; ++bt)
                    bfr[bt] = *(const bf16x8*)&bufp[(((brr[bt] + taprow) * 4 + q) * 34 + bcol[bt] + dx) * 8];
#pragma unroll
                for (int at = 0; at < 4; ++at)
#pragma unroll
                    for (int bt = 0; bt < 4; ++bt)
                        acc[at][bt] = __builtin_amdgcn_mfma_f32_16x16x32_bf16(afc[at], bfr[bt],
                                                                              acc[at][bt], 0, 0, 0);
                if (t < 8) {
#pragma unroll
                    for (int at = 0; at < 4; ++at) afc[at] = afn[at];
                }
            }
        } else {
            bf16x8 afA[NT][4];
#pragma unroll
            for (int t = 0; t < NT; ++t)
#pragma unroll
                for (int at = 0; at < 4; ++at)
                    afA[t][at] = *(const bf16x8*)(wb + (long)t * 65536 + at * 512);
#pragma unroll
            for (int t = 0; t < NT; ++t) {
                int taprow, dx;
                if (MODE == 1) { taprow = 0; dx = 0; }
                else { taprow = t >> 1; dx = (t & 1) - ph_w; }
                bf16x8 bfr[4];
#pragma unroll
                for (int bt = 0; bt < 4; ++bt)
                    bfr[bt] = *(const bf16x8*)&bufp[(((brr[bt] + taprow) * 4 + q) * 34 + bcol[bt] + dx) * 8];
#pragma unroll
                for (int at = 0; at < 4; ++at)
#pragma unroll
                    for (int bt = 0; bt < 4; ++bt)
                        acc[at][bt] = __builtin_amdgcn_mfma_f32_16x16x32_bf16(afA[t][at], bfr[bt],
                                                                              acc[at][bt], 0, 0, 0);
            }
        }

        if (it + 1 < NITER) write_stage((it + 1) & 1);
    }

    // ---- epilogue (all-bf16) ----
    int co_base = coslab * 64;
#pragma unroll
    for (int at = 0; at < 4; ++at) {
        int co_t = co_base + at * 16 + q * 4;
        float bv[4] = {0.f, 0.f, 0.f, 0.f};
        if (HAS_BIAS) {
            float4 b4 = *(const float4*)(bias + co_t);
            bv[0] = b4.x; bv[1] = b4.y; bv[2] = b4.z; bv[3] = b4.w;
        }
#pragma unroll
        for (int bt = 0; bt < 4; ++bt) {
            int m = R0 * 32 + bt * 16 + l15;          // global pixel index
            long oaddr = ((long)n * 1024 + m) * 256 + co_t;
            float v[4];
#pragma unroll
            for (int r = 0; r < 4; ++r) v[r] = acc[at][bt][r] + bv[r];
            if (ADD_RES) {
                uint2 rr = *(const uint2*)(res + ((long)n * 1024 + m) * 256 + co_t);
                v[0] += bfl(rr.x); v[1] += bfh(rr.x);
                v[2] += bfl(rr.y); v[3] += bfh(rr.y);
            }
            if (RELU_OUT) {
#pragma unroll
                for (int r = 0; r < 4; ++r) v[r] = fmaxf(v[r], 0.f);
            }
            uint2 pk;
            pk.x = (unsigned)f2bf(v[0]) | ((unsigned)f2bf(v[1]) << 16);
            pk.y = (unsigned)f2bf(v[2]) | ((unsigned)f2bf(v[3]) << 16);
            *(uint2*)(obf + oaddr) = pk;
        }
    }
}

// ======================= VQ via MFMA (bf16 out) =======================
__global__ __launch_bounds__(256) void k_vq2(const ushort* __restrict__ zb,
                                             const ushort* __restrict__ apk,
                                             const float* __restrict__ en,
                                             const float* __restrict__ cbf,
                                             ushort* __restrict__ vqb,
                                             float* __restrict__ loss) {
    __shared__ int sIdx[64];
    __shared__ float sLoss[64];
    int tid = threadIdx.x, lane = tid & 63, wv = tid >> 6;
    int q = lane >> 4, l15 = lane & 15;
    int r0 = blockIdx.x * 64;
    int R = r0 + wv * 16;

    const ushort* zp = zb + ((long)(R + l15)) * 64 + q * 8;
    bf16x8 b0 = *(const bf16x8*)zp;
    bf16x8 b1 = *(const bf16x8*)(zp + 32);

    float z2 = 0.f;
    {
        const unsigned* u0 = (const unsigned*)&b0;
        const unsigned* u1 = (const unsigned*)&b1;
#pragma unroll
        for (int i = 0; i < 4; ++i) {
            float a = bfl(u0[i]), bb = bfh(u0[i]);
            float c = bfl(u1[i]), d = bfh(u1[i]);
            z2 += a * a + bb * bb + c * c + d * d;
        }
    }

    float best = 3.4e38f;
    int bidx = 0;
#pragma unroll
    for (int t = 0; t < 16; ++t) {
        bf16x8 a0 = *(const bf16x8*)(apk + ((t * 2 + 0) * 64 + lane) * 8);
        bf16x8 a1 = *(const bf16x8*)(apk + ((t * 2 + 1) * 64 + lane) * 8);
        f32x4 acc = {0.f, 0.f, 0.f, 0.f};
        acc = __builtin_amdgcn_mfma_f32_16x16x32_bf16(a0, b0, acc, 0, 0, 0);
        acc = __builtin_amdgcn_mfma_f32_16x16x32_bf16(a1, b1, acc, 0, 0, 0);
        float4 e4 = *(const float4*)(en + t * 16 + q * 4);
        float sc[4] = {e4.x - 2.f * acc[0], e4.y - 2.f * acc[1],
                       e4.z - 2.f * acc[2], e4.w - 2.f * acc[3]};
#pragma unroll
        for (int r = 0; r < 4; ++r) {
            int code = t * 16 + q * 4 + r;
            if (sc[r] < best) { best = sc[r]; bidx = code; }
        }
    }
#pragma unroll
    for (int m = 16; m <= 32; m <<= 1) {
        float ob = __shfl_xor(best, m);
        int oi = __shfl_xor(bidx, m);
        if (ob < best || (ob == best && oi < bidx)) { best = ob; bidx = oi; }
        z2 += __shfl_xor(z2, m);
    }
    if (q == 0) {
        sIdx[wv * 16 + l15] = bidx;
        sLoss[wv * 16 + l15] = best + z2;
    }
    __syncthreads();

    if (wv == 0) {
        float l = sLoss[lane];
#pragma unroll
        for (int m = 1; m < 64; m <<= 1) l += __shfl_xor(l, m);
        if (lane == 0) atomicAdd(loss, l * (1.25f / 8388608.f));
    }

    unsigned* vb = (unsigned*)(vqb + (long)r0 * 64);
#pragma unroll
    for (int k = 0; k < 8; ++k) {
        int i = k * 256 + tid;
        int rl = i >> 5, jp = i & 31;
        int idx = sIdx[rl];
        float v0 = cbf[idx * 64 + 2 * jp];
        float v1 = cbf[idx * 64 + 2 * jp + 1];
        vb[i] = (unsigned)f2bf(v0) | ((unsigned)f2bf(v1) << 16);
    }
}

// ======================= composed decoder deconv: 256->3 k10 s4, 32->128 ========
// Wave-private double-buffered LDS, barrier-free (mconv idiom). 1 U-row/wave,
// M=16 phase rows, 3 co-MFMAs share each B-frag. tanh epilogue, f32 out.
__global__ __launch_bounds__(128, 2) void k_dec_comp(const ushort* __restrict__ xin,
                                                     const ushort* __restrict__ wdec,
                                                     const float* __restrict__ bdec,
                                                     float* __restrict__ out) {
    constexpr int BUFU = 3 * 4 * 34 * 8;             // 3264 ushorts
    constexpr int WLDS = 2 * BUFU;
    __shared__ __align__(16) ushort sX[2 * WLDS];    // 26112 B

    int tid = threadIdx.x, lane = tid & 63, wv = tid >> 6;
    int q = lane >> 4, l15 = lane & 15;
    int b = blockIdx.x;                              // 32n * 16rp
    int rp = b & 15, n = b >> 4;
    int U = rp * 2 + wv;
    ushort* sW = sX + wv * WLDS;

    if (lane < 48) {                                 // zero col pads, both bufs
        int cc = (lane & 1) ? 33 : 0;
        int sq = lane >> 1;
        uint4 z; z.x = z.y = z.z = z.w = 0;
        *(uint4*)&sW[(sq * 34 + cc) * 8] = z;
    }
    int scol = lane >> 1, j0 = (lane & 1) * 2;

    f32x4 acc[3][2];
#pragma unroll
    for (int o = 0; o < 3; ++o)
#pragma unroll
        for (int bt = 0; bt < 2; ++bt) acc[o][bt] = 0.f;

    uint4 sreg[3][2];
    auto stage_load = [&](int cb2) {
#pragma unroll
        for (int r = 0; r < 3; ++r) {
            int hh = U - 1 + r;
            bool valid = (unsigned)hh < 32u;
            long off = (((long)n * 32 + hh) * 32 + scol) * 256 + cb2 * 32 + j0 * 8;
#pragma unroll
            for (int k = 0; k < 2; ++k) {
                uint4 v;
                if (valid) v = *(const uint4*)(xin + off + k * 8);
                else { v.x = 0; v.y = 0; v.z = 0; v.w = 0; }
                sreg[r][k] = v;
            }
        }
    };
    auto write_stage = [&](int pbuf) {
        ushort* bufp = sW + pbuf * BUFU;
#pragma unroll
        for (int r = 0; r < 3; ++r)
#pragma unroll
            for (int k = 0; k < 2; ++k)
                *(uint4*)&bufp[((r * 4 + j0 + k) * 34 + scol + 1) * 8] = sreg[r][k];
    };

    stage_load(0);
    write_stage(0);

    for (int cb = 0; cb < 8; ++cb) {
        ushort* bufp = sW + (cb & 1) * BUFU;
        if (cb + 1 < 8) stage_load(cb + 1);
        const ushort* wb = wdec + (long)cb * 512 + l15 * 32 + q * 8;
#pragma unroll
        for (int t = 0; t < 9; ++t) {
            int du = t / 3 - 1, dv = t % 3 - 1;
            bf16x8 bfr[2];
#pragma unroll
            for (int bt = 0; bt < 2; ++bt)
                bfr[bt] = *(const bf16x8*)&bufp[(((du + 1) * 4 + q) * 34 + bt * 16 + l15 + 1 + dv) * 8];
#pragma unroll
            for (int o = 0; o < 3; ++o) {
                bf16x8 af = *(const bf16x8*)(wb + (long)(t * 3 + o) * 4096);
#pragma unroll
                for (int bt = 0; bt < 2; ++bt)
                    acc[o][bt] = __builtin_amdgcn_mfma_f32_16x16x32_bf16(af, bfr[bt], acc[o][bt], 0, 0, 0);
            }
        }
        if (cb + 1 < 8) write_stage((cb + 1) & 1);
    }

    // epilogue: D row = phase p = q*4+r, col = pixel V; scatter + tanh
#pragma unroll
    for (int o = 0; o < 3; ++o) {
#pragma unroll
        for (int bt = 0; bt < 2; ++bt) {
            int V = bt * 16 + l15;
#pragma unroll
            for (int r = 0; r < 4; ++r) {
                int p = q * 4 + r, py = p >> 2, px = p & 3;
                out[(((long)n * 3 + o) * 128 + 4 * U + py) * 128 + 4 * V + px] =
                    tanhf(acc[o][bt][r] + bdec[o * 16 + p]);
            }
        }
    }
}

// ======================= launcher =======================
extern "C" void kernel_launch(void* const* d_in, const int* in_sizes, int n_in,
                              void* d_out, int out_size, void* d_ws, size_t ws_size,
                              hipStream_t stream) {
    (void)in_sizes; (void)n_in; (void)out_size; (void)ws_size;
    const float* x        = (const float*)d_in[0];
    const float* enc_w1   = (const float*)d_in[1];
    const float* enc_b1   = (const float*)d_in[2];
    const float* enc_w2   = (const float*)d_in[3];
    const float* enc_b2   = (const float*)d_in[4];
    const float* er1_w3   = (const float*)d_in[5];
    const float* er1_w1   = (const float*)d_in[6];
    const float* er2_w3   = (const float*)d_in[7];
    const float* er2_w1   = (const float*)d_in[8];
    const float* codebook = (const float*)d_in[9];
    const float* dr1_w3   = (const float*)d_in[10];
    const float* dr1_w1   = (const float*)d_in[11];
    const float* dr2_w3   = (const float*)d_in[12];
    const float* dr2_w1   = (const float*)d_in[13];
    const float* dt1_w    = (const float*)d_in[14];
    const float* dt1_b    = (const float*)d_in[15];
    const float* dt2_w    = (const float*)d_in[16];
    const float* dt2_b    = (const float*)d_in[17];

    float* recon = (float*)d_out;
    float* loss  = recon + 1572864;

    char* ws = (char*)d_ws;
    size_t off = 0;
    auto alloc = [&](size_t bytes) { char* p = ws + off; off += (bytes + 255) & ~(size_t)255; return p; };
    ushort* N64  = (ushort*)alloc(67108864);   // [32,64,64,256] bf16
    ushort* X0   = (ushort*)alloc(16777216);   // bf16 NHWC 32x32 tensors
    ushort* X1   = (ushort*)alloc(16777216);
    ushort* X2   = (ushort*)alloc(16777216);
    ushort* X3   = (ushort*)alloc(16777216);
    ushort* X4   = (ushort*)alloc(16777216);
    ushort* wpk_c2   = (ushort*)alloc(2097152);
    ushort* wpk_er13 = (ushort*)alloc(1179648);
    ushort* wpk_er23 = (ushort*)alloc(1179648);
    ushort* wpk_dr13 = (ushort*)alloc(1179648);
    ushort* wpk_dr23 = (ushort*)alloc(1179648);
    ushort* wpk_er11 = (ushort*)alloc(131072);
    ushort* wpk_er21 = (ushort*)alloc(131072);
    ushort* wpk_dr11 = (ushort*)alloc(131072);
    ushort* wpk_dr21 = (ushort*)alloc(131072);
    float*  wt_c1    = (float*)alloc(49152);
    ushort* wdec     = (ushort*)alloc(221184); // [9][3][8][16][32] bf16
    ushort* apk      = (ushort*)alloc(32768);
    float*  bdec     = (float*)alloc(192);
    float*  en       = (float*)alloc(1024);

    hipMemsetAsync(loss, 0, sizeof(float), stream);
    hipMemsetAsync(wdec, 0, 221184, stream);

    // weight packing
    k_pack_c1f<<<48, 256, 0, stream>>>(enc_w1, wt_c1);
    k_pack_c2<<<4096, 256, 0, stream>>>(enc_w2, wpk_c2);
    k_pack_c3x4<<<9216, 256, 0, stream>>>(er1_w3, er2_w3, dr1_w3, dr2_w3,
                                          wpk_er13, wpk_er23, wpk_dr13, wpk_dr23);
    k_pack_c1x1x4<<<1024, 256, 0, stream>>>(er1_w1, er2_w1, dr1_w1, dr2_w1,
                                            wpk_er11, wpk_er21, wpk_dr11, wpk_dr21);
    k_pack_vq<<<65, 256, 0, stream>>>(codebook, apk, en);
    k_wcomp_dec<<<256, 256, 0, stream>>>(dt1_w, dt1_b, dt2_w, dt2_b, wdec, bdec);

    // encoder (verified two-stage)
    k_conv1n<<<2048, 256, 0, stream>>>(x, wt_c1, enc_b1, N64);
    k_mconv<2, true, false, false, false><<<1024, 128, 0, stream>>>(N64, wpk_c2, enc_b2, nullptr, X0);
    // er1: 3x3(relu-stage) X0 -> X1(relu'd) ; 1x1 X1 + res X0 -> X2
    k_mconv<0, false, false, true, true><<<1024, 128, 0, stream>>>(X0, wpk_er13, nullptr, nullptr, X1);
    k_mconv<1, false, true, false, false><<<1024, 128, 0, stream>>>(X1, wpk_er11, nullptr, X0, X2);
    // er2: X2 -> X1 ; X1 + res X2 -> X3 (z, VQ input)
    k_mconv<0, false, false, true, true><<<1024, 128, 0, stream>>>(X2, wpk_er23, nullptr, nullptr, X1);
    k_mconv<1, false, true, false, false><<<1024, 128, 0, stream>>>(X1, wpk_er21, nullptr, X2, X3);
    // VQ: X3 -> X4 (vq, no relu) + loss
    k_vq2<<<2048, 256, 0, stream>>>(X3, apk, en, codebook, X4, loss);
    // dr1: X4 -> X1 ; X1 + res X4 -> X0
    k_mconv<0, false, false, true, true><<<1024, 128, 0, stream>>>(X4, wpk_dr13, nullptr, nullptr, X1);
    k_mconv<1, false, true, false, false><<<1024, 128, 0, stream>>>(X1, wpk_dr11, nullptr, X4, X0);
    // dr2: X0 -> X1 ; X1 + res X0 -> X2
    k_mconv<0, false, false, true, true><<<1024, 128, 0, stream>>>(X0, wpk_dr23, nullptr, nullptr, X1);
    k_mconv<1, false, true, false, false><<<1024, 128, 0, stream>>>(X1, wpk_dr21, nullptr, X0, X2);
    // decoder (composed deconv1∘deconv2 + tanh): X2 -> recon
    k_dec_comp<<<512, 128, 0, stream>>>(X2, wdec, bdec, recon);
}

// Round 3
// 648.791 us; speedup vs baseline: 1.2081x; 1.1003x over previous
//
#include <hip/hip_runtime.h>
#include <math.h>

// VQ-VAE forward. R15: fused res-block kernel (3x3 -> relu -> 1x1 -> +res in
// one launch, LDS exchange, no X1 tensor). Encoder two-stage (verified R12),
// composed decoder (verified R14). conv2 + vq + dec_comp byte-identical.

typedef unsigned short ushort;
typedef short bf16x8 __attribute__((ext_vector_type(8)));
typedef float f32x4 __attribute__((ext_vector_type(4)));

__device__ __forceinline__ ushort f2bf(float f) {
    unsigned u = __builtin_bit_cast(unsigned, f);
    unsigned r = (u + 0x7fffu + ((u >> 16) & 1u)) >> 16;
    return (ushort)r;
}
__device__ __forceinline__ float bfl(unsigned u) { return __builtin_bit_cast(float, u << 16); }
__device__ __forceinline__ float bfh(unsigned u) { return __builtin_bit_cast(float, u & 0xffff0000u); }

__device__ __forceinline__ unsigned relu_u(unsigned u) {
    unsigned m = (u >> 15) & 0x00010001u;
    return u & ~((m << 16) - m);
}
__device__ __forceinline__ uint4 relu4(uint4 v) {
    v.x = relu_u(v.x); v.y = relu_u(v.y); v.z = relu_u(v.z); v.w = relu_u(v.w);
    return v;
}

// ======================= weight packing =======================
// MFMA layout (per layer): [cls][tap][cb(8)][co(256)][k(32)] bf16.

__global__ void k_pack_c3x4(const float* __restrict__ w0, const float* __restrict__ w1,
                            const float* __restrict__ w2, const float* __restrict__ w3,
                            ushort* __restrict__ o0, ushort* __restrict__ o1,
                            ushort* __restrict__ o2, ushort* __restrict__ o3) {
    int layer = blockIdx.x / 2304;
    int i = (blockIdx.x - layer * 2304) * 256 + threadIdx.x;     // 589824
    const float* w = layer == 0 ? w0 : layer == 1 ? w1 : layer == 2 ? w2 : w3;
    ushort* o = layer == 0 ? o0 : layer == 1 ? o1 : layer == 2 ? o2 : o3;
    int kk = i & 31, co = (i >> 5) & 255, cb = (i >> 13) & 7, t = i >> 16;
    int ci = cb * 32 + kk, kh = t / 3, kw = t % 3;
    o[i] = f2bf(w[((co * 256 + ci) * 3 + kh) * 3 + kw]);
}

__global__ void k_pack_c1x1x4(const float* __restrict__ w0, const float* __restrict__ w1,
                              const float* __restrict__ w2, const float* __restrict__ w3,
                              ushort* __restrict__ o0, ushort* __restrict__ o1,
                              ushort* __restrict__ o2, ushort* __restrict__ o3) {
    int layer = blockIdx.x >> 8;
    int i = (blockIdx.x & 255) * 256 + threadIdx.x;              // 65536
    const float* w = layer == 0 ? w0 : layer == 1 ? w1 : layer == 2 ? w2 : w3;
    ushort* o = layer == 0 ? o0 : layer == 1 ? o1 : layer == 2 ? o2 : o3;
    int kk = i & 31, co = (i >> 5) & 255, cb = (i >> 13) & 7;
    o[i] = f2bf(w[co * 256 + cb * 32 + kk]);
}

// conv2 4x4s2 pack: [cls(4 phase)][tap(4)][cb(8)][co(256)][k(32)]
__global__ void k_pack_c2(const float* __restrict__ wc2, ushort* __restrict__ oc2) {
    int i = blockIdx.x * 256 + threadIdx.x;                      // 1048576
    int kk = i & 31, co = (i >> 5) & 255, cb = (i >> 13) & 7;
    int t = (i >> 16) & 3, cls = i >> 18;
    int a = t >> 1, b = t & 1, ci = cb * 32 + kk;
    int ph = cls >> 1, pw = cls & 1;
    int kh = ph ? 2 * a : 2 * a + 1;
    int kw = pw ? 2 * b : 2 * b + 1;
    oc2[i] = f2bf(wc2[((co * 256 + ci) * 4 + kh) * 4 + kw]);
}

__global__ void k_pack_c1f(const float* __restrict__ w, float* __restrict__ o) {
    int i = blockIdx.x * 256 + threadIdx.x;           // 12288
    int co = i & 255, k = i >> 8;
    int ci = k >> 4, kh = (k >> 2) & 3, kw = k & 3;
    o[k * 256 + co] = w[((co * 3 + ci) * 4 + kh) * 4 + kw];
}

__global__ void k_pack_vq(const float* __restrict__ cb, ushort* __restrict__ apk,
                          float* __restrict__ en) {
    if (blockIdx.x < 64) {
        int i = blockIdx.x * 256 + threadIdx.x;
        int j = i & 7, lane = (i >> 3) & 63, s = (i >> 9) & 1, t = i >> 10;
        int code = t * 16 + (lane & 15);
        int dim = s * 32 + (lane >> 4) * 8 + j;
        apk[i] = f2bf(cb[code * 64 + dim]);
    } else {
        int code = threadIdx.x;
        float s = 0.f;
        for (int d = 0; d < 64; ++d) { float v = cb[code * 64 + d]; s += v * v; }
        en[code] = s;
    }
}

// ======================= decoder weight composition =======================
__global__ __launch_bounds__(256) void k_wcomp_dec(const float* __restrict__ dt1,
                                                   const float* __restrict__ dt1b,
                                                   const float* __restrict__ dt2,
                                                   const float* __restrict__ dt2b,
                                                   ushort* __restrict__ wdec,
                                                   float* __restrict__ bdec) {
    __shared__ float s1[4096];     // dt1[ci][m][a][b] slice (16KB)
    __shared__ float s2[12288];    // dt2[m][o][c][d]        (49KB)
    __shared__ float part[2400];
    int ci = blockIdx.x, tid = threadIdx.x;
    for (int i = tid; i < 4096; i += 256) s1[i] = dt1[ci * 4096 + i];
    for (int i = tid; i < 12288; i += 256) s2[i] = dt2[i];
    __syncthreads();

    if (ci == 0 && tid < 48) {     // composed bias per (o, phase)
        int o = tid >> 4, p = tid & 15, py = p >> 2, px = p & 3;
        int c0 = (py + 1) & 1, d0 = (px + 1) & 1;
        float s = dt2b[o];
        for (int m = 0; m < 256; ++m) {
            float t2 = s2[m * 48 + o * 16 + c0 * 4 + d0] + s2[m * 48 + o * 16 + c0 * 4 + d0 + 2]
                     + s2[m * 48 + o * 16 + (c0 + 2) * 4 + d0] + s2[m * 48 + o * 16 + (c0 + 2) * 4 + d0 + 2];
            s += dt1b[m] * t2;
        }
        bdec[tid] = s;
    }

    if (tid < 240) {               // t = y*24 + o*8 + ms
        int y = tid / 24, rem = tid % 24, o = rem / 8, ms = rem % 8;
        int na = 0, aa[2], cc[2];
#pragma unroll
        for (int a = 0; a < 4; ++a) {
            int c = y - 2 * a;
            if ((unsigned)c < 4u) { aa[na] = a; cc[na] = c; ++na; }
        }
        float acc10[10];
#pragma unroll
        for (int xx = 0; xx < 10; ++xx) acc10[xx] = 0.f;
        for (int m = ms * 32; m < ms * 32 + 32; ++m) {
            for (int pa = 0; pa < na; ++pa) {
                float4 d1 = *(const float4*)&s1[m * 16 + aa[pa] * 4];
                float4 d2 = *(const float4*)&s2[m * 48 + o * 16 + cc[pa] * 4];
                acc10[0] += d1.x * d2.x; acc10[1] += d1.x * d2.y; acc10[2] += d1.x * d2.z; acc10[3] += d1.x * d2.w;
                acc10[2] += d1.y * d2.x; acc10[3] += d1.y * d2.y; acc10[4] += d1.y * d2.z; acc10[5] += d1.y * d2.w;
                acc10[4] += d1.z * d2.x; acc10[5] += d1.z * d2.y; acc10[6] += d1.z * d2.z; acc10[7] += d1.z * d2.w;
                acc10[6] += d1.w * d2.x; acc10[7] += d1.w * d2.y; acc10[8] += d1.w * d2.z; acc10[9] += d1.w * d2.w;
            }
        }
#pragma unroll
        for (int xx = 0; xx < 10; ++xx) part[tid * 10 + xx] = acc10[xx];
    }
    __syncthreads();
    if (tid < 300) {
        int y = tid / 30, r = tid % 30, o = r / 10, xx = r % 10;
        float s = 0.f;
#pragma unroll
        for (int ms = 0; ms < 8; ++ms) s += part[((y * 24 + o * 8) + ms) * 10 + xx];
        int du = (y < 3) ? 1 : (y < 7) ? 0 : -1;
        int py = y - 3 + 4 * du;
        int dv = (xx < 3) ? 1 : (xx < 7) ? 0 : -1;
        int px = xx - 3 + 4 * dv;
        int t = (du + 1) * 3 + (dv + 1);
        int cb2 = ci >> 5, kk = ci & 31;
        wdec[((((t * 3 + o) * 8 + cb2) * 16 + py * 4 + px) * 32) + kk] = f2bf(s);
    }
}

// ======================= conv1: 3->256 k4 s2, 128->64, LDS-staged ==============
__global__ __launch_bounds__(256) void k_conv1n(const float* __restrict__ x,
                                                const float* __restrict__ wt,
                                                const float* __restrict__ bias,
                                                ushort* __restrict__ o) {       // NHWC64 bf16
    __shared__ float sx[12][132];
    int b = blockIdx.x;                  // 32n * 64h
    int h = b & 63, n = b >> 6;
    int tid = threadIdx.x;
    for (int c = tid; c < 12 * 128; c += 256) {
        int t = c >> 7, wi = c & 127;
        int ci = t >> 2, kh = t & 3;
        int hi = 2 * h - 1 + kh;
        float v = ((unsigned)hi < 128u) ? x[((long)n * 3 + ci) * 16384 + hi * 128 + wi] : 0.f;
        sx[t][wi + 1] = v;
    }
    if (tid < 24) { int t = tid >> 1; sx[t][(tid & 1) ? 129 : 0] = 0.f; }
    int co = tid;
    float wr[48];
#pragma unroll
    for (int k = 0; k < 48; ++k) wr[k] = wt[k * 256 + co];
    float bco = bias[co];
    __syncthreads();
    ushort* op = o + (((long)n * 64 + h) * 64) * 256 + co;
    for (int w = 0; w < 64; ++w) {
        float acc = bco;
#pragma unroll
        for (int t = 0; t < 12; ++t) {
            const float* xr = &sx[t][2 * w];
            acc += xr[0] * wr[t * 4] + xr[1] * wr[t * 4 + 1]
                 + xr[2] * wr[t * 4 + 2] + xr[3] * wr[t * 4 + 3];
        }
        op[w * 256] = f2bf(acc);
    }
}

// ======================= wave-private barrier-free MFMA conv (conv2 only) =======
template <int MODE, bool HAS_BIAS, bool ADD_RES, bool RELU_STAGE, bool RELU_OUT>
__global__ __launch_bounds__(128, 2) void k_mconv(const ushort* __restrict__ xin,
                                                  const ushort* __restrict__ wpk,
                                                  const float* __restrict__ bias,
                                                  const ushort* __restrict__ res,
                                                  ushort* __restrict__ obf) {
    constexpr int NT = (MODE == 0) ? 9 : ((MODE == 1) ? 1 : 4);
    constexpr int NITER = (MODE == 2) ? 32 : 8;
    constexpr int NR = (MODE == 0) ? 4 : ((MODE == 1) ? 2 : 3);
    constexpr int BUFU = NR * 4 * 34 * 8;
    constexpr int WLDS = 2 * BUFU;

    __shared__ __align__(16) ushort sX[2 * WLDS];

    int tid = threadIdx.x, lane = tid & 63, wv = tid >> 6;
    int q = lane >> 4, l15 = lane & 15;
    int b = blockIdx.x;
    int mblk = b & 7, coslab = (b >> 3) & 3;
    int n = b >> 5;
    int R0 = mblk * 4 + wv * 2;

    ushort* sW = sX + wv * WLDS;

    if (lane < 2 * NR * 4 * 2) {
        int cc = (lane & 1) ? 33 : 0;
        int sq = lane >> 1;
        uint4 z; z.x = z.y = z.z = z.w = 0;
        *(uint4*)&sW[(sq * 34 + cc) * 8] = z;
    }

    int brr[4], bcol[4];
#pragma unroll
    for (int bt = 0; bt < 4; ++bt) {
        int p = bt * 16 + l15;
        brr[bt] = p >> 5; bcol[bt] = (p & 31) + 1;
    }

    int scol = lane >> 1, j0 = (lane & 1) * 2;
    int aoff = (coslab * 64 + l15) * 32 + q * 8;

    f32x4 acc[4][4];
#pragma unroll
    for (int at = 0; at < 4; ++at)
#pragma unroll
        for (int bt = 0; bt < 4; ++bt) acc[at][bt] = 0.f;

    uint4 sreg[NR][2];
    auto stage_load = [&](int it2) {
        int cb2 = (MODE == 2) ? (it2 >> 2) : it2;
        int ph2 = (MODE == 2) ? (it2 & 3) : 0;
        int ph_h2 = ph2 >> 1, ph_w2 = ph2 & 1;
        int hh0 = (MODE == 0) ? R0 - 1 : (MODE == 1) ? R0 : R0 - ph_h2;
#pragma unroll
        for (int r = 0; r < NR; ++r) {
            int hh = hh0 + r;
            bool valid = (unsigned)hh < 32u;
            long off;
            if (MODE == 2)
                off = (((long)n * 64 + 2 * hh + ph_h2) * 64 + (2 * scol + ph_w2)) * 256 + cb2 * 32 + j0 * 8;
            else
                off = (((long)n * 32 + hh) * 32 + scol) * 256 + cb2 * 32 + j0 * 8;
#pragma unroll
            for (int k = 0; k < 2; ++k) {
                uint4 v;
                if (valid) {
                    v = *(const uint4*)(xin + off + k * 8);
                    if (RELU_STAGE) v = relu4(v);
                } else { v.x = 0; v.y = 0; v.z = 0; v.w = 0; }
                sreg[r][k] = v;
            }
        }
    };
    auto write_stage = [&](int pbuf) {
        ushort* bufp = sW + pbuf * BUFU;
#pragma unroll
        for (int r = 0; r < NR; ++r)
#pragma unroll
            for (int k = 0; k < 2; ++k)
                *(uint4*)&bufp[((r * 4 + j0 + k) * 34 + scol + 1) * 8] = sreg[r][k];
    };

    stage_load(0);
    write_stage(0);

    for (int it = 0; it < NITER; ++it) {
        int cb = (MODE == 2) ? (it >> 2) : it;
        int ph = (MODE == 2) ? (it & 3) : 0;
        int ph_w = ph & 1;
        int clsi = (MODE == 2) ? ph : 0;
        const ushort* wb = wpk + ((long)(clsi * NT) * 8 + cb) * 8192 + aoff;
        ushort* bufp = sW + (it & 1) * BUFU;

        if (it + 1 < NITER) stage_load(it + 1);

        if (MODE == 0) {
            bf16x8 afc[4];
#pragma unroll
            for (int at = 0; at < 4; ++at) afc[at] = *(const bf16x8*)(wb + at * 512);
#pragma unroll
            for (int t = 0; t < 9; ++t) {
                bf16x8 afn[4];
                if (t < 8) {
#pragma unroll
                    for (int at = 0; at < 4; ++at)
                        afn[at] = *(const bf16x8*)(wb + (long)(t + 1) * 65536 + at * 512);
                }
                int taprow = t / 3, dx = t % 3 - 1;
                bf16x8 bfr[4];
#pragma unroll
                for (int bt = 0; bt < 4; ++bt)
                    bfr[bt] = *(const bf16x8*)&bufp[(((brr[bt] + taprow) * 4 + q) * 34 + bcol[bt] + dx) * 8];
#pragma unroll
                for (int at = 0; at < 4; ++at)
#pragma unroll
                    for (int bt = 0; bt < 4; ++bt)
                        acc[at][bt] = __builtin_amdgcn_mfma_f32_16x16x32_bf16(afc[at], bfr[bt],
                                                                              acc[at][bt], 0, 0, 0);
                if (t < 8) {
#pragma unroll
                    for (int at = 0; at < 4; ++at) afc[at] = afn[at];
                }
            }
        } else {
            bf16x8 afA[NT][4];
#pragma unroll
            for (int t = 0; t < NT; ++t)
#pragma unroll
                for (int at = 0; at < 4; ++at)
                    afA[t][at] = *(const bf16x8*)(wb + (long)t * 65536 + at * 512);
#pragma unroll
            for (int t = 0; t < NT; ++t) {
                int taprow, dx;
                if (MODE == 1) { taprow = 0; dx = 0; }
                else { taprow = t >> 1; dx = (t & 1) - ph_w; }
                bf16x8 bfr[4];
#pragma unroll
                for (int bt = 0; bt < 4; ++bt)
                    bfr[bt] = *(const bf16x8*)&bufp[(((brr[bt] + taprow) * 4 + q) * 34 + bcol[bt] + dx) * 8];
#pragma unroll
                for (int at = 0; at < 4; ++at)
#pragma unroll
                    for (int bt = 0; bt < 4; ++bt)
                        acc[at][bt] = __builtin_amdgcn_mfma_f32_16x16x32_bf16(afA[t][at], bfr[bt],
                                                                              acc[at][bt], 0, 0, 0);
            }
        }

        if (it + 1 < NITER) write_stage((it + 1) & 1);
    }

    int co_base = coslab * 64;
#pragma unroll
    for (int at = 0; at < 4; ++at) {
        int co_t = co_base + at * 16 + q * 4;
        float bv[4] = {0.f, 0.f, 0.f, 0.f};
        if (HAS_BIAS) {
            float4 b4 = *(const float4*)(bias + co_t);
            bv[0] = b4.x; bv[1] = b4.y; bv[2] = b4.z; bv[3] = b4.w;
        }
#pragma unroll
        for (int bt = 0; bt < 4; ++bt) {
            int m = R0 * 32 + bt * 16 + l15;
            long oaddr = ((long)n * 1024 + m) * 256 + co_t;
            float v[4];
#pragma unroll
            for (int r = 0; r < 4; ++r) v[r] = acc[at][bt][r] + bv[r];
            if (ADD_RES) {
                uint2 rr = *(const uint2*)(res + ((long)n * 1024 + m) * 256 + co_t);
                v[0] += bfl(rr.x); v[1] += bfh(rr.x);
                v[2] += bfl(rr.y); v[3] += bfh(rr.y);
            }
            if (RELU_OUT) {
#pragma unroll
                for (int r = 0; r < 4; ++r) v[r] = fmaxf(v[r], 0.f);
            }
            uint2 pk;
            pk.x = (unsigned)f2bf(v[0]) | ((unsigned)f2bf(v[1]) << 16);
            pk.y = (unsigned)f2bf(v[2]) | ((unsigned)f2bf(v[3]) << 16);
            *(uint2*)(obf + oaddr) = pk;
        }
    }
}

// ======================= fused res block =======================
// out = x + conv1x1(relu(conv3x3(relu(x)))), all in one kernel.
// Block: 256 thr = 4 waves; tile 256co x 64px (2 rows x 32 cols); wave w owns
// co slab [w*64, w*64+64). Cooperative double-buffered staging (wave w stages
// input row w of the 4-row window; ONE barrier per cb iteration is sufficient:
// at iteration cb every wave has passed the end-of-(cb-1) barrier, so all
// reads of buf[(cb+1)&1] (done in cb-1) are complete -> WAR safe; the write ->
// barrier -> read of iteration cb+1 gives RAW). 3x3 output (relu, bf16) goes
// to LDS exchange ex[px 64][ci 256] with octet XOR swizzle ci^((px&7)<<3)
// (same involution on write and read; bits 0..2 untouched so uint2/bf16x8
// blocks stay contiguous; read conflict-free, write 2-way=free).
__global__ __launch_bounds__(256, 2) void k_resblock(const ushort* __restrict__ xin,
                                                     const ushort* __restrict__ w3pk,
                                                     const ushort* __restrict__ w1pk,
                                                     ushort* __restrict__ obf) {
    constexpr int BUFU = 4 * 4 * 34 * 8;             // 4352 ushorts = 8704 B
    __shared__ __align__(16) ushort sX[2 * BUFU];    // 17408 B staging
    __shared__ __align__(16) ushort sEx[64 * 256];   // 32768 B exchange

    int tid = threadIdx.x, lane = tid & 63, wv = tid >> 6;
    int q = lane >> 4, l15 = lane & 15;
    int b = blockIdx.x;                              // 32n * 16 rowpairs
    int rp = b & 15, n = b >> 4;
    int R0 = rp * 2;

    // zero col pads of both staging buffers (wave 0)
    if (tid < 64) {
        int bufi = tid >> 5, rq = (tid >> 1) & 15, cc = (tid & 1) ? 33 : 0;
        uint4 z; z.x = z.y = z.z = z.w = 0;
        *(uint4*)&sX[bufi * BUFU + (rq * 34 + cc) * 8] = z;
    }

    int brr[4], bcol[4];
#pragma unroll
    for (int bt = 0; bt < 4; ++bt) {
        int p = bt * 16 + l15;
        brr[bt] = p >> 5; bcol[bt] = (p & 31) + 1;
    }

    int scol = lane >> 1, j0 = (lane & 1) * 2;
    int aoff = (wv * 64 + l15) * 32 + q * 8;

    f32x4 acc[4][4];
#pragma unroll
    for (int at = 0; at < 4; ++at)
#pragma unroll
        for (int bt = 0; bt < 4; ++bt) acc[at][bt] = 0.f;

    // cooperative staging: wave w loads input row R0-1+w of channel slab cb
    int hh = R0 - 1 + wv;
    bool hvalid = (unsigned)hh < 32u;
    uint4 sreg[2];
    auto stage_load = [&](int cb2) {
        long off = (((long)n * 32 + hh) * 32 + scol) * 256 + cb2 * 32 + j0 * 8;
#pragma unroll
        for (int k = 0; k < 2; ++k) {
            uint4 v;
            if (hvalid) v = relu4(*(const uint4*)(xin + off + k * 8));
            else { v.x = 0; v.y = 0; v.z = 0; v.w = 0; }
            sreg[k] = v;
        }
    };
    auto write_stage = [&](int pbuf) {
        ushort* bufp = sX + pbuf * BUFU;
#pragma unroll
        for (int k = 0; k < 2; ++k)
            *(uint4*)&bufp[((wv * 4 + j0 + k) * 34 + scol + 1) * 8] = sreg[k];
    };

    stage_load(0);
    write_stage(0);
    __syncthreads();                                 // pads + buf0 visible

    // ---- 3x3 over 8 ci-octet slabs ----
    for (int cb = 0; cb < 8; ++cb) {
        ushort* bufp = sX + (cb & 1) * BUFU;
        if (cb + 1 < 8) stage_load(cb + 1);
        const ushort* wb = w3pk + (long)cb * 8192 + aoff;

        bf16x8 afc[4];
#pragma unroll
        for (int at = 0; at < 4; ++at) afc[at] = *(const bf16x8*)(wb + at * 512);
#pragma unroll
        for (int t = 0; t < 9; ++t) {
            bf16x8 afn[4];
            if (t < 8) {
#pragma unroll
                for (int at = 0; at < 4; ++at)
                    afn[at] = *(const bf16x8*)(wb + (long)(t + 1) * 65536 + at * 512);
            }
            int taprow = t / 3, dx = t % 3 - 1;
            bf16x8 bfr[4];
#pragma unroll
            for (int bt = 0; bt < 4; ++bt)
                bfr[bt] = *(const bf16x8*)&bufp[(((brr[bt] + taprow) * 4 + q) * 34 + bcol[bt] + dx) * 8];
#pragma unroll
            for (int at = 0; at < 4; ++at)
#pragma unroll
                for (int bt = 0; bt < 4; ++bt)
                    acc[at][bt] = __builtin_amdgcn_mfma_f32_16x16x32_bf16(afc[at], bfr[bt],
                                                                          acc[at][bt], 0, 0, 0);
            if (t < 8) {
#pragma unroll
                for (int at = 0; at < 4; ++at) afc[at] = afn[at];
            }
        }

        if (cb + 1 < 8) {
            write_stage((cb + 1) & 1);
            __syncthreads();
        }
    }

    // ---- 3x3 epilogue: relu -> bf16 -> exchange LDS ----
#pragma unroll
    for (int at = 0; at < 4; ++at) {
        int co_t = wv * 64 + at * 16 + q * 4;
#pragma unroll
        for (int bt = 0; bt < 4; ++bt) {
            int px = bt * 16 + l15;
            uint2 pk;
            pk.x = (unsigned)f2bf(fmaxf(acc[at][bt][0], 0.f))
                 | ((unsigned)f2bf(fmaxf(acc[at][bt][1], 0.f)) << 16);
            pk.y = (unsigned)f2bf(fmaxf(acc[at][bt][2], 0.f))
                 | ((unsigned)f2bf(fmaxf(acc[at][bt][3], 0.f)) << 16);
            *(uint2*)&sEx[px * 256 + (co_t ^ ((px & 7) << 3))] = pk;
        }
    }
    __syncthreads();

    // ---- 1x1 over 8 ci-octet slabs from exchange ----
    f32x4 acc2[4][4];
#pragma unroll
    for (int at = 0; at < 4; ++at)
#pragma unroll
        for (int bt = 0; bt < 4; ++bt) acc2[at][bt] = 0.f;

    for (int cb = 0; cb < 8; ++cb) {
        const ushort* wb1 = w1pk + (long)cb * 8192 + aoff;
        bf16x8 af1[4];
#pragma unroll
        for (int at = 0; at < 4; ++at) af1[at] = *(const bf16x8*)(wb1 + at * 512);
        bf16x8 bf1[4];
#pragma unroll
        for (int bt = 0; bt < 4; ++bt) {
            int px = bt * 16 + l15;
            bf1[bt] = *(const bf16x8*)&sEx[px * 256 + ((cb * 32 + q * 8) ^ ((px & 7) << 3))];
        }
#pragma unroll
        for (int at = 0; at < 4; ++at)
#pragma unroll
            for (int bt = 0; bt < 4; ++bt)
                acc2[at][bt] = __builtin_amdgcn_mfma_f32_16x16x32_bf16(af1[at], bf1[bt],
                                                                      acc2[at][bt], 0, 0, 0);
    }

    // ---- final epilogue: + residual (raw input), bf16 store ----
#pragma unroll
    for (int at = 0; at < 4; ++at) {
        int co_t = wv * 64 + at * 16 + q * 4;
#pragma unroll
        for (int bt = 0; bt < 4; ++bt) {
            int m = R0 * 32 + bt * 16 + l15;
            long oaddr = ((long)n * 1024 + m) * 256 + co_t;
            uint2 rr = *(const uint2*)(xin + oaddr);
            float v[4];
            v[0] = acc2[at][bt][0] + bfl(rr.x);
            v[1] = acc2[at][bt][1] + bfh(rr.x);
            v[2] = acc2[at][bt][2] + bfl(rr.y);
            v[3] = acc2[at][bt][3] + bfh(rr.y);
            uint2 pk;
            pk.x = (unsigned)f2bf(v[0]) | ((unsigned)f2bf(v[1]) << 16);
            pk.y = (unsigned)f2bf(v[2]) | ((unsigned)f2bf(v[3]) << 16);
            *(uint2*)(obf + oaddr) = pk;
        }
    }
}

// ======================= VQ via MFMA (bf16 out) =======================
__global__ __launch_bounds__(256) void k_vq2(const ushort* __restrict__ zb,
                                             const ushort* __restrict__ apk,
                                             const float* __restrict__ en,
                                             const float* __restrict__ cbf,
                                             ushort* __restrict__ vqb,
                                             float* __restrict__ loss) {
    __shared__ int sIdx[64];
    __shared__ float sLoss[64];
    int tid = threadIdx.x, lane = tid & 63, wv = tid >> 6;
    int q = lane >> 4, l15 = lane & 15;
    int r0 = blockIdx.x * 64;
    int R = r0 + wv * 16;

    const ushort* zp = zb + ((long)(R + l15)) * 64 + q * 8;
    bf16x8 b0 = *(const bf16x8*)zp;
    bf16x8 b1 = *(const bf16x8*)(zp + 32);

    float z2 = 0.f;
    {
        const unsigned* u0 = (const unsigned*)&b0;
        const unsigned* u1 = (const unsigned*)&b1;
#pragma unroll
        for (int i = 0; i < 4; ++i) {
            float a = bfl(u0[i]), bb = bfh(u0[i]);
            float c = bfl(u1[i]), d = bfh(u1[i]);
            z2 += a * a + bb * bb + c * c + d * d;
        }
    }

    float best = 3.4e38f;
    int bidx = 0;
#pragma unroll
    for (int t = 0; t < 16; ++t) {
        bf16x8 a0 = *(const bf16x8*)(apk + ((t * 2 + 0) * 64 + lane) * 8);
        bf16x8 a1 = *(const bf16x8*)(apk + ((t * 2 + 1) * 64 + lane) * 8);
        f32x4 acc = {0.f, 0.f, 0.f, 0.f};
        acc = __builtin_amdgcn_mfma_f32_16x16x32_bf16(a0, b0, acc, 0, 0, 0);
        acc = __builtin_amdgcn_mfma_f32_16x16x32_bf16(a1, b1, acc, 0, 0, 0);
        float4 e4 = *(const float4*)(en + t * 16 + q * 4);
        float sc[4] = {e4.x - 2.f * acc[0], e4.y - 2.f * acc[1],
                       e4.z - 2.f * acc[2], e4.w - 2.f * acc[3]};
#pragma unroll
        for (int r = 0; r < 4; ++r) {
            int code = t * 16 + q * 4 + r;
            if (sc[r] < best) { best = sc[r]; bidx = code; }
        }
    }
#pragma unroll
    for (int m = 16; m <= 32; m <<= 1) {
        float ob = __shfl_xor(best, m);
        int oi = __shfl_xor(bidx, m);
        if (ob < best || (ob == best && oi < bidx)) { best = ob; bidx = oi; }
        z2 += __shfl_xor(z2, m);
    }
    if (q == 0) {
        sIdx[wv * 16 + l15] = bidx;
        sLoss[wv * 16 + l15] = best + z2;
    }
    __syncthreads();

    if (wv == 0) {
        float l = sLoss[lane];
#pragma unroll
        for (int m = 1; m < 64; m <<= 1) l += __shfl_xor(l, m);
        if (lane == 0) atomicAdd(loss, l * (1.25f / 8388608.f));
    }

    unsigned* vb = (unsigned*)(vqb + (long)r0 * 64);
#pragma unroll
    for (int k = 0; k < 8; ++k) {
        int i = k * 256 + tid;
        int rl = i >> 5, jp = i & 31;
        int idx = sIdx[rl];
        float v0 = cbf[idx * 64 + 2 * jp];
        float v1 = cbf[idx * 64 + 2 * jp + 1];
        vb[i] = (unsigned)f2bf(v0) | ((unsigned)f2bf(v1) << 16);
    }
}

// ======================= composed decoder deconv: 256->3 k10 s4, 32->128 ========
__global__ __launch_bounds__(128, 2) void k_dec_comp(const ushort* __restrict__ xin,
                                                     const ushort* __restrict__ wdec,
                                                     const float* __restrict__ bdec,
                                                     float* __restrict__ out) {
    constexpr int BUFU = 3 * 4 * 34 * 8;             // 3264 ushorts
    constexpr int WLDS = 2 * BUFU;
    __shared__ __align__(16) ushort sX[2 * WLDS];    // 26112 B

    int tid = threadIdx.x, lane = tid & 63, wv = tid >> 6;
    int q = lane >> 4, l15 = lane & 15;
    int b = blockIdx.x;                              // 32n * 16rp
    int rp = b & 15, n = b >> 4;
    int U = rp * 2 + wv;
    ushort* sW = sX + wv * WLDS;

    if (lane < 48) {
        int cc = (lane & 1) ? 33 : 0;
        int sq = lane >> 1;
        uint4 z; z.x = z.y = z.z = z.w = 0;
        *(uint4*)&sW[(sq * 34 + cc) * 8] = z;
    }
    int scol = lane >> 1, j0 = (lane & 1) * 2;

    f32x4 acc[3][2];
#pragma unroll
    for (int o = 0; o < 3; ++o)
#pragma unroll
        for (int bt = 0; bt < 2; ++bt) acc[o][bt] = 0.f;

    uint4 sreg[3][2];
    auto stage_load = [&](int cb2) {
#pragma unroll
        for (int r = 0; r < 3; ++r) {
            int hh = U - 1 + r;
            bool valid = (unsigned)hh < 32u;
            long off = (((long)n * 32 + hh) * 32 + scol) * 256 + cb2 * 32 + j0 * 8;
#pragma unroll
            for (int k = 0; k < 2; ++k) {
                uint4 v;
                if (valid) v = *(const uint4*)(xin + off + k * 8);
                else { v.x = 0; v.y = 0; v.z = 0; v.w = 0; }
                sreg[r][k] = v;
            }
        }
    };
    auto write_stage = [&](int pbuf) {
        ushort* bufp = sW + pbuf * BUFU;
#pragma unroll
        for (int r = 0; r < 3; ++r)
#pragma unroll
            for (int k = 0; k < 2; ++k)
                *(uint4*)&bufp[((r * 4 + j0 + k) * 34 + scol + 1) * 8] = sreg[r][k];
    };

    stage_load(0);
    write_stage(0);

    for (int cb = 0; cb < 8; ++cb) {
        ushort* bufp = sX + wv * WLDS + (cb & 1) * BUFU;
        if (cb + 1 < 8) stage_load(cb + 1);
        const ushort* wb = wdec + (long)cb * 512 + l15 * 32 + q * 8;
#pragma unroll
        for (int t = 0; t < 9; ++t) {
            int du = t / 3 - 1, dv = t % 3 - 1;
            bf16x8 bfr[2];
#pragma unroll
            for (int bt = 0; bt < 2; ++bt)
                bfr[bt] = *(const bf16x8*)&bufp[(((du + 1) * 4 + q) * 34 + bt * 16 + l15 + 1 + dv) * 8];
#pragma unroll
            for (int o = 0; o < 3; ++o) {
                bf16x8 af = *(const bf16x8*)(wb + (long)(t * 3 + o) * 4096);
#pragma unroll
                for (int bt = 0; bt < 2; ++bt)
                    acc[o][bt] = __builtin_amdgcn_mfma_f32_16x16x32_bf16(af, bfr[bt], acc[o][bt], 0, 0, 0);
            }
        }
        if (cb + 1 < 8) write_stage((cb + 1) & 1);
    }

#pragma unroll
    for (int o = 0; o < 3; ++o) {
#pragma unroll
        for (int bt = 0; bt < 2; ++bt) {
            int V = bt * 16 + l15;
#pragma unroll
            for (int r = 0; r < 4; ++r) {
                int p = q * 4 + r, py = p >> 2, px = p & 3;
                out[(((long)n * 3 + o) * 128 + 4 * U + py) * 128 + 4 * V + px] =
                    tanhf(acc[o][bt][r] + bdec[o * 16 + p]);
            }
        }
    }
}

// ======================= launcher =======================
extern "C" void kernel_launch(void* const* d_in, const int* in_sizes, int n_in,
                              void* d_out, int out_size, void* d_ws, size_t ws_size,
                              hipStream_t stream) {
    (void)in_sizes; (void)n_in; (void)out_size; (void)ws_size;
    const float* x        = (const float*)d_in[0];
    const float* enc_w1   = (const float*)d_in[1];
    const float* enc_b1   = (const float*)d_in[2];
    const float* enc_w2   = (const float*)d_in[3];
    const float* enc_b2   = (const float*)d_in[4];
    const float* er1_w3   = (const float*)d_in[5];
    const float* er1_w1   = (const float*)d_in[6];
    const float* er2_w3   = (const float*)d_in[7];
    const float* er2_w1   = (const float*)d_in[8];
    const float* codebook = (const float*)d_in[9];
    const float* dr1_w3   = (const float*)d_in[10];
    const float* dr1_w1   = (const float*)d_in[11];
    const float* dr2_w3   = (const float*)d_in[12];
    const float* dr2_w1   = (const float*)d_in[13];
    const float* dt1_w    = (const float*)d_in[14];
    const float* dt1_b    = (const float*)d_in[15];
    const float* dt2_w    = (const float*)d_in[16];
    const float* dt2_b    = (const float*)d_in[17];

    float* recon = (float*)d_out;
    float* loss  = recon + 1572864;

    char* ws = (char*)d_ws;
    size_t off = 0;
    auto alloc = [&](size_t bytes) { char* p = ws + off; off += (bytes + 255) & ~(size_t)255; return p; };
    ushort* N64  = (ushort*)alloc(67108864);   // [32,64,64,256] bf16
    ushort* X0   = (ushort*)alloc(16777216);   // bf16 NHWC 32x32 tensors
    ushort* X2   = (ushort*)alloc(16777216);
    ushort* X3   = (ushort*)alloc(16777216);
    ushort* X4   = (ushort*)alloc(16777216);
    ushort* wpk_c2   = (ushort*)alloc(2097152);
    ushort* wpk_er13 = (ushort*)alloc(1179648);
    ushort* wpk_er23 = (ushort*)alloc(1179648);
    ushort* wpk_dr13 = (ushort*)alloc(1179648);
    ushort* wpk_dr23 = (ushort*)alloc(1179648);
    ushort* wpk_er11 = (ushort*)alloc(131072);
    ushort* wpk_er21 = (ushort*)alloc(131072);
    ushort* wpk_dr11 = (ushort*)alloc(131072);
    ushort* wpk_dr21 = (ushort*)alloc(131072);
    float*  wt_c1    = (float*)alloc(49152);
    ushort* wdec     = (ushort*)alloc(221184); // [9][3][8][16][32] bf16
    ushort* apk      = (ushort*)alloc(32768);
    float*  bdec     = (float*)alloc(192);
    float*  en       = (float*)alloc(1024);

    hipMemsetAsync(loss, 0, sizeof(float), stream);
    hipMemsetAsync(wdec, 0, 221184, stream);

    // weight packing
    k_pack_c1f<<<48, 256, 0, stream>>>(enc_w1, wt_c1);
    k_pack_c2<<<4096, 256, 0, stream>>>(enc_w2, wpk_c2);
    k_pack_c3x4<<<9216, 256, 0, stream>>>(er1_w3, er2_w3, dr1_w3, dr2_w3,
                                          wpk_er13, wpk_er23, wpk_dr13, wpk_dr23);
    k_pack_c1x1x4<<<1024, 256, 0, stream>>>(er1_w1, er2_w1, dr1_w1, dr2_w1,
                                            wpk_er11, wpk_er21, wpk_dr11, wpk_dr21);
    k_pack_vq<<<65, 256, 0, stream>>>(codebook, apk, en);
    k_wcomp_dec<<<256, 256, 0, stream>>>(dt1_w, dt1_b, dt2_w, dt2_b, wdec, bdec);

    // encoder (verified two-stage)
    k_conv1n<<<2048, 256, 0, stream>>>(x, wt_c1, enc_b1, N64);
    k_mconv<2, true, false, false, false><<<1024, 128, 0, stream>>>(N64, wpk_c2, enc_b2, nullptr, X0);
    // fused res blocks (encoder)
    k_resblock<<<512, 256, 0, stream>>>(X0, wpk_er13, wpk_er11, X2);
    k_resblock<<<512, 256, 0, stream>>>(X2, wpk_er23, wpk_er21, X3);
    // VQ: X3 -> X4 (vq, no relu) + loss
    k_vq2<<<2048, 256, 0, stream>>>(X3, apk, en, codebook, X4, loss);
    // fused res blocks (decoder)
    k_resblock<<<512, 256, 0, stream>>>(X4, wpk_dr13, wpk_dr11, X0);
    k_resblock<<<512, 256, 0, stream>>>(X0, wpk_dr23, wpk_dr21, X2);
    // decoder (composed deconv1∘deconv2 + tanh): X2 -> recon
    k_dec_comp<<<512, 128, 0, stream>>>(X2, wdec, bdec, recon);
}